// Round 1
// baseline (572.760 us; speedup 1.0000x reference)
//
#include <hip/hip_runtime.h>
#include <hip/hip_fp16.h>
#include <math.h>

#define BATCH 16
#define NQ 2048
#define NK 2048
#define DIM 512
#define QK_SCALE 0.044194173824159216f  // 1/sqrt(512)

#define BM 128
#define BN 128
#define BK 32

typedef _Float16 f16x8 __attribute__((ext_vector_type(8)));
typedef _Float16 f16x4 __attribute__((ext_vector_type(4)));
typedef float f32x4 __attribute__((ext_vector_type(4)));

// ---------------------------------------------------------------------------
// Kernel 1: fp32 -> fp16 conversion of q and k into workspace
// ---------------------------------------------------------------------------
__global__ __launch_bounds__(256) void convert_f32_to_f16(
    const float4* __restrict__ q, const float4* __restrict__ k,
    f16x4* __restrict__ qh, f16x4* __restrict__ kh, int n4_each)
{
    int stride = gridDim.x * blockDim.x;
    for (int i = blockIdx.x * blockDim.x + threadIdx.x; i < 2 * n4_each; i += stride) {
        float4 v;
        f16x4* dst;
        if (i < n4_each) { v = q[i]; dst = qh + i; }
        else             { v = k[i - n4_each]; dst = kh + (i - n4_each); }
        f16x4 o;
        o[0] = (_Float16)v.x; o[1] = (_Float16)v.y;
        o[2] = (_Float16)v.z; o[3] = (_Float16)v.w;
        *dst = o;
    }
}

// ---------------------------------------------------------------------------
// Kernel 2: scores = Q K^T * scale ; p = exp(scores) ; rowsum += p (atomics)
// 128x128 tile, BK=32, 4 waves (2x2), 16x16x32 f16 MFMA, double-buffered LDS,
// global_load_lds width-16 staging (m97 structure).
// ---------------------------------------------------------------------------
__global__ __launch_bounds__(256, 2) void qk_exp_gemm(
    const _Float16* __restrict__ qh, const _Float16* __restrict__ kh,
    float* __restrict__ out, float* __restrict__ rowsum)
{
    __shared__ _Float16 As[2][BM * BK];
    __shared__ _Float16 Bs[2][BN * BK];

    const int tid  = threadIdx.x;
    const int lane = tid & 63;
    const int w    = tid >> 6;       // wave id 0..3
    const int wr   = w >> 1;         // wave row 0..1
    const int wc   = w & 1;          // wave col 0..1
    const int bz   = blockIdx.z;
    const int brow = blockIdx.y * BM;
    const int bcol = blockIdx.x * BN;

    const _Float16* qbase = qh + (size_t)(bz * NQ + brow) * DIM;
    const _Float16* kbase = kh + (size_t)(bz * NK + bcol) * DIM;

    const int lr = lane & 15;   // row-in-frag (A) / col-in-frag (B)
    const int ls = lane >> 4;   // k-slot 0..3

    // stage one BK-slice of A and B into LDS buffer `buf` for k-tile t.
    // Each wave stages chunks {2w, 2w+1}: chunk = 64 lanes x 16B = 1KB = 16 rows.
    auto stage = [&](int buf, int t) {
        const int k0 = t * BK;
#pragma unroll
        for (int i = 0; i < 2; ++i) {
            const int c    = w * 2 + i;          // chunk 0..7
            const int row  = c * 16 + (lane >> 2);
            const int slot = lane & 3;
            const _Float16* ga = qbase + row * DIM + k0 + slot * 8;
            const _Float16* gb = kbase + row * DIM + k0 + slot * 8;
            __builtin_amdgcn_global_load_lds(
                (const __attribute__((address_space(1))) void*)ga,
                (__attribute__((address_space(3))) void*)&As[buf][c * 512 + lane * 8],
                16, 0, 0);
            __builtin_amdgcn_global_load_lds(
                (const __attribute__((address_space(1))) void*)gb,
                (__attribute__((address_space(3))) void*)&Bs[buf][c * 512 + lane * 8],
                16, 0, 0);
        }
    };

    f32x4 acc[4][4] = {};

    stage(0, 0);
    __syncthreads();

    const int NT = DIM / BK;  // 16
    for (int t = 0; t < NT; ++t) {
        const int buf = t & 1;
        if (t + 1 < NT) stage(buf ^ 1, t + 1);

        f16x8 a[4], b[4];
#pragma unroll
        for (int mi = 0; mi < 4; ++mi) {
            const int r = wr * 64 + mi * 16 + lr;
            a[mi] = *(const f16x8*)&As[buf][r * BK + ls * 8];
        }
#pragma unroll
        for (int nj = 0; nj < 4; ++nj) {
            const int c = wc * 64 + nj * 16 + lr;
            b[nj] = *(const f16x8*)&Bs[buf][c * BK + ls * 8];
        }
#pragma unroll
        for (int mi = 0; mi < 4; ++mi)
#pragma unroll
            for (int nj = 0; nj < 4; ++nj)
                acc[mi][nj] = __builtin_amdgcn_mfma_f32_16x16x32_f16(
                    a[mi], b[nj], acc[mi][nj], 0, 0, 0);

        __syncthreads();
    }

    // Epilogue: p = exp(score*scale); store p; reduce row partial sums; atomic.
    // C/D layout (verified m89): col = lane&15, row = (lane>>4)*4 + reg.
    float* outb = out + (size_t)bz * NQ * NK;
#pragma unroll
    for (int mi = 0; mi < 4; ++mi) {
#pragma unroll
        for (int r = 0; r < 4; ++r) {
            const int rowl = wr * 64 + mi * 16 + ls * 4 + r;
            const int grow = brow + rowl;
            float psum = 0.f;
#pragma unroll
            for (int nj = 0; nj < 4; ++nj) {
                const int gcol = bcol + wc * 64 + nj * 16 + lr;
                float p = expf(acc[mi][nj][r] * QK_SCALE);
                psum += p;
                outb[(size_t)grow * NK + gcol] = p;
            }
#pragma unroll
            for (int off = 1; off < 16; off <<= 1)
                psum += __shfl_xor(psum, off, 64);
            if (lr == 0)
                atomicAdd(&rowsum[bz * NQ + grow], psum);
        }
    }
}

// ---------------------------------------------------------------------------
// Kernel 3: out[i] /= rowsum[row]
// ---------------------------------------------------------------------------
__global__ __launch_bounds__(256) void softmax_norm(
    float4* __restrict__ out, const float* __restrict__ rowsum, int n4)
{
    int stride = gridDim.x * blockDim.x;
    for (int i = blockIdx.x * blockDim.x + threadIdx.x; i < n4; i += stride) {
        const int row = i >> 9;  // (i*4)/2048
        const float inv = 1.0f / rowsum[row];
        float4 v = out[i];
        v.x *= inv; v.y *= inv; v.z *= inv; v.w *= inv;
        out[i] = v;
    }
}

// ---------------------------------------------------------------------------
extern "C" void kernel_launch(void* const* d_in, const int* in_sizes, int n_in,
                              void* d_out, int out_size, void* d_ws, size_t ws_size,
                              hipStream_t stream)
{
    const float* q = (const float*)d_in[0];
    const float* k = (const float*)d_in[1];
    float* out = (float*)d_out;

    const size_t elems = (size_t)BATCH * NQ * DIM;  // 16,777,216 per tensor
    _Float16* qh = (_Float16*)d_ws;
    _Float16* kh = qh + elems;
    float* rowsum = (float*)(kh + elems);           // at +64 MB

    hipMemsetAsync(rowsum, 0, BATCH * NQ * sizeof(float), stream);

    const int n4_each = (int)(elems / 4);
    convert_f32_to_f16<<<2048, 256, 0, stream>>>(
        (const float4*)q, (const float4*)k, (f16x4*)qh, (f16x4*)kh, n4_each);

    dim3 grid(NK / BN, NQ / BM, BATCH);
    qk_exp_gemm<<<grid, 256, 0, stream>>>(qh, kh, out, rowsum);

    const int n4o = (int)((size_t)BATCH * NQ * NK / 4);
    softmax_norm<<<2048, 256, 0, stream>>>((float4*)out, rowsum, n4o);
}

// Round 2
// 530.729 us; speedup vs baseline: 1.0792x; 1.0792x over previous
//
#include <hip/hip_runtime.h>
#include <hip/hip_fp16.h>
#include <math.h>

#define BATCH 16
#define NQ 2048
#define NK 2048
#define DIM 512
// exp(s * 1/sqrt(512)) == exp2(s * QK_SCALE * log2(e))
#define EXP2_SCALE (0.044194173824159216f * 1.4426950408889634f)

#define BM 128
#define BN 128
#define BK 32

typedef _Float16 f16x8 __attribute__((ext_vector_type(8)));
typedef _Float16 f16x4 __attribute__((ext_vector_type(4)));
typedef float f32x4 __attribute__((ext_vector_type(4)));

// ---------------------------------------------------------------------------
// Kernel 1: fp32 -> fp16 conversion of q and k into workspace
// ---------------------------------------------------------------------------
__global__ __launch_bounds__(256) void convert_f32_to_f16(
    const float4* __restrict__ q, const float4* __restrict__ k,
    f16x4* __restrict__ qh, f16x4* __restrict__ kh, int n4_each)
{
    int stride = gridDim.x * blockDim.x;
    for (int i = blockIdx.x * blockDim.x + threadIdx.x; i < 2 * n4_each; i += stride) {
        float4 v;
        f16x4* dst;
        if (i < n4_each) { v = q[i]; dst = qh + i; }
        else             { v = k[i - n4_each]; dst = kh + (i - n4_each); }
        f16x4 o;
        o[0] = (_Float16)v.x; o[1] = (_Float16)v.y;
        o[2] = (_Float16)v.z; o[3] = (_Float16)v.w;
        *dst = o;
    }
}

// ---------------------------------------------------------------------------
// Kernel 2: p = exp2(score * EXP2_SCALE) stored as fp16 ; rowsum += p
// 128x128 tile, BK=32, 4 waves (2x2), 16x16x32 f16 MFMA, double-buffered LDS,
// global_load_lds width-16 staging (m97 structure) + XCD-aware plane swizzle.
// ---------------------------------------------------------------------------
__global__ __launch_bounds__(256, 2) void qk_exp_gemm(
    const _Float16* __restrict__ qh, const _Float16* __restrict__ kh,
    _Float16* __restrict__ ph, float* __restrict__ rowsum)
{
    __shared__ _Float16 As[2][BM * BK];
    __shared__ _Float16 Bs[2][BN * BK];

    const int tid  = threadIdx.x;
    const int lane = tid & 63;
    const int w    = tid >> 6;       // wave id 0..3
    const int wr   = w >> 1;         // wave row 0..1
    const int wc   = w & 1;          // wave col 0..1
    const int bz   = blockIdx.z;

    // T1: XCD-aware swizzle within the 16x16 plane (256 blocks, 256%8==0).
    // Blocks with the same (lin%8) land on the same XCD (round-robin dispatch);
    // remap so each XCD covers 2 contiguous row-bands x all col tiles ->
    // per-batch K matrix (2MB fp16) is L2-resident per XCD.
    const int lin = blockIdx.y * 16 + blockIdx.x;
    const int swz = (lin & 7) * 32 + (lin >> 3);
    const int brow = (swz >> 4) * BM;
    const int bcol = (swz & 15) * BN;

    const _Float16* qbase = qh + (size_t)(bz * NQ + brow) * DIM;
    const _Float16* kbase = kh + (size_t)(bz * NK + bcol) * DIM;

    const int lr = lane & 15;   // row-in-frag (A) / col-in-frag (B)
    const int ls = lane >> 4;   // k-slot 0..3

    auto stage = [&](int buf, int t) {
        const int k0 = t * BK;
#pragma unroll
        for (int i = 0; i < 2; ++i) {
            const int c    = w * 2 + i;          // chunk 0..7
            const int row  = c * 16 + (lane >> 2);
            const int slot = lane & 3;
            const _Float16* ga = qbase + row * DIM + k0 + slot * 8;
            const _Float16* gb = kbase + row * DIM + k0 + slot * 8;
            __builtin_amdgcn_global_load_lds(
                (const __attribute__((address_space(1))) void*)ga,
                (__attribute__((address_space(3))) void*)&As[buf][c * 512 + lane * 8],
                16, 0, 0);
            __builtin_amdgcn_global_load_lds(
                (const __attribute__((address_space(1))) void*)gb,
                (__attribute__((address_space(3))) void*)&Bs[buf][c * 512 + lane * 8],
                16, 0, 0);
        }
    };

    f32x4 acc[4][4] = {};

    stage(0, 0);
    __syncthreads();

    const int NT = DIM / BK;  // 16
    for (int t = 0; t < NT; ++t) {
        const int buf = t & 1;
        if (t + 1 < NT) stage(buf ^ 1, t + 1);

        f16x8 a[4], b[4];
#pragma unroll
        for (int mi = 0; mi < 4; ++mi) {
            const int r = wr * 64 + mi * 16 + lr;
            a[mi] = *(const f16x8*)&As[buf][r * BK + ls * 8];
        }
#pragma unroll
        for (int nj = 0; nj < 4; ++nj) {
            const int c = wc * 64 + nj * 16 + lr;
            b[nj] = *(const f16x8*)&Bs[buf][c * BK + ls * 8];
        }
#pragma unroll
        for (int mi = 0; mi < 4; ++mi)
#pragma unroll
            for (int nj = 0; nj < 4; ++nj)
                acc[mi][nj] = __builtin_amdgcn_mfma_f32_16x16x32_f16(
                    a[mi], b[nj], acc[mi][nj], 0, 0, 0);

        __syncthreads();
    }

    // Epilogue. C/D layout: col = lane&15, row = (lane>>4)*4 + reg.
    _Float16* pb = ph + (size_t)bz * NQ * NK;
#pragma unroll
    for (int mi = 0; mi < 4; ++mi) {
#pragma unroll
        for (int r = 0; r < 4; ++r) {
            const int rowl = wr * 64 + mi * 16 + ls * 4 + r;
            const int grow = brow + rowl;
            float psum = 0.f;
#pragma unroll
            for (int nj = 0; nj < 4; ++nj) {
                const int gcol = bcol + wc * 64 + nj * 16 + lr;
                float p = __builtin_amdgcn_exp2f(acc[mi][nj][r] * EXP2_SCALE);
                psum += p;
                pb[(size_t)grow * NK + gcol] = (_Float16)p;
            }
#pragma unroll
            for (int off = 1; off < 16; off <<= 1)
                psum += __shfl_xor(psum, off, 64);
            if (lr == 0)
                atomicAdd(&rowsum[bz * NQ + grow], psum);
        }
    }
}

// ---------------------------------------------------------------------------
// Kernel 3: out[i] = p[i] / rowsum[row]   (fp16 in, fp32 out, 8 elems/thread)
// ---------------------------------------------------------------------------
__global__ __launch_bounds__(256) void softmax_norm(
    const f16x8* __restrict__ ph, const float* __restrict__ rowsum,
    float4* __restrict__ out, int n8)
{
    int stride = gridDim.x * blockDim.x;
    for (int i = blockIdx.x * blockDim.x + threadIdx.x; i < n8; i += stride) {
        const int row = i >> 8;  // 2048/8 = 256 vec8 per row
        const float inv = 1.0f / rowsum[row];
        f16x8 v = ph[i];
        float4 o0, o1;
        o0.x = (float)v[0] * inv; o0.y = (float)v[1] * inv;
        o0.z = (float)v[2] * inv; o0.w = (float)v[3] * inv;
        o1.x = (float)v[4] * inv; o1.y = (float)v[5] * inv;
        o1.z = (float)v[6] * inv; o1.w = (float)v[7] * inv;
        out[i * 2]     = o0;
        out[i * 2 + 1] = o1;
    }
}

// ---------------------------------------------------------------------------
extern "C" void kernel_launch(void* const* d_in, const int* in_sizes, int n_in,
                              void* d_out, int out_size, void* d_ws, size_t ws_size,
                              hipStream_t stream)
{
    const float* q = (const float*)d_in[0];
    const float* k = (const float*)d_in[1];
    float* out = (float*)d_out;

    const size_t elems = (size_t)BATCH * NQ * DIM;   // 16,777,216 per tensor
    const size_t pelems = (size_t)BATCH * NQ * NK;   // 67,108,864
    _Float16* qh = (_Float16*)d_ws;
    _Float16* kh = qh + elems;
    _Float16* ph = kh + elems;                       // +64 MB, 128 MB long
    float* rowsum = (float*)(ph + pelems);           // +192 MB

    hipMemsetAsync(rowsum, 0, BATCH * NQ * sizeof(float), stream);

    const int n4_each = (int)(elems / 4);
    convert_f32_to_f16<<<2048, 256, 0, stream>>>(
        (const float4*)q, (const float4*)k, (f16x4*)qh, (f16x4*)kh, n4_each);

    dim3 grid(NK / BN, NQ / BM, BATCH);
    qk_exp_gemm<<<grid, 256, 0, stream>>>(qh, kh, ph, rowsum);

    const int n8 = (int)(pelems / 8);
    softmax_norm<<<2048, 256, 0, stream>>>(
        (const f16x8*)ph, rowsum, (float4*)out, n8);
}

// Round 3
// 528.785 us; speedup vs baseline: 1.0832x; 1.0037x over previous
//
#include <hip/hip_runtime.h>
#include <hip/hip_fp16.h>
#include <math.h>

#define BATCH 16
#define NQ 2048
#define NK 2048
#define DIM 512
// exp(s / sqrt(512)) == exp2(s * EXP2_SCALE)
#define EXP2_SCALE (0.044194173824159216f * 1.4426950408889634f)

#define BM 128
#define BN 128
#define BK 32

typedef _Float16 f16x8 __attribute__((ext_vector_type(8)));
typedef _Float16 f16x4 __attribute__((ext_vector_type(4)));
typedef float f32x4 __attribute__((ext_vector_type(4)));

// ---------------------------------------------------------------------------
// Kernel 1: fp32 -> fp16 conversion of q and k into workspace
// ---------------------------------------------------------------------------
__global__ __launch_bounds__(256) void convert_f32_to_f16(
    const float4* __restrict__ q, const float4* __restrict__ k,
    f16x4* __restrict__ qh, f16x4* __restrict__ kh, int n4_each)
{
    int stride = gridDim.x * blockDim.x;
    for (int i = blockIdx.x * blockDim.x + threadIdx.x; i < 2 * n4_each; i += stride) {
        float4 v;
        f16x4* dst;
        if (i < n4_each) { v = q[i]; dst = qh + i; }
        else             { v = k[i - n4_each]; dst = kh + (i - n4_each); }
        f16x4 o;
        o[0] = (_Float16)v.x; o[1] = (_Float16)v.y;
        o[2] = (_Float16)v.z; o[3] = (_Float16)v.w;
        *dst = o;
    }
}

// ---------------------------------------------------------------------------
// Kernel 2: p = exp2(score * EXP2_SCALE) stored fp16 (coalesced via LDS
// bounce); rowsum += p. m97 structure k-loop (unchanged from round 2).
// ---------------------------------------------------------------------------
__global__ __launch_bounds__(256, 2) void qk_exp_gemm(
    const _Float16* __restrict__ qh, const _Float16* __restrict__ kh,
    _Float16* __restrict__ ph, float* __restrict__ rowsum)
{
    __shared__ _Float16 As[2][BM * BK];
    __shared__ _Float16 Bs[2][BN * BK];
    __shared__ _Float16 Ps[32 * 128];   // epilogue bounce tile, XOR-swizzled

    const int tid  = threadIdx.x;
    const int lane = tid & 63;
    const int w    = tid >> 6;       // wave id 0..3
    const int wr   = w >> 1;         // wave row 0..1
    const int wc   = w & 1;          // wave col 0..1
    const int bz   = blockIdx.z;

    // XCD-aware swizzle within the 16x16 plane (256 blocks, 256%8==0).
    const int lin = blockIdx.y * 16 + blockIdx.x;
    const int swz = (lin & 7) * 32 + (lin >> 3);
    const int brow = (swz >> 4) * BM;
    const int bcol = (swz & 15) * BN;

    const _Float16* qbase = qh + (size_t)(bz * NQ + brow) * DIM;
    const _Float16* kbase = kh + (size_t)(bz * NK + bcol) * DIM;

    const int lr = lane & 15;   // row-in-frag (A) / col-in-frag (B)
    const int ls = lane >> 4;   // k-slot 0..3

    auto stage = [&](int buf, int t) {
        const int k0 = t * BK;
#pragma unroll
        for (int i = 0; i < 2; ++i) {
            const int c    = w * 2 + i;          // chunk 0..7
            const int row  = c * 16 + (lane >> 2);
            const int slot = lane & 3;
            const _Float16* ga = qbase + row * DIM + k0 + slot * 8;
            const _Float16* gb = kbase + row * DIM + k0 + slot * 8;
            __builtin_amdgcn_global_load_lds(
                (const __attribute__((address_space(1))) void*)ga,
                (__attribute__((address_space(3))) void*)&As[buf][c * 512 + lane * 8],
                16, 0, 0);
            __builtin_amdgcn_global_load_lds(
                (const __attribute__((address_space(1))) void*)gb,
                (__attribute__((address_space(3))) void*)&Bs[buf][c * 512 + lane * 8],
                16, 0, 0);
        }
    };

    f32x4 acc[4][4] = {};

    stage(0, 0);
    __syncthreads();

    const int NT = DIM / BK;  // 16
    for (int t = 0; t < NT; ++t) {
        const int buf = t & 1;
        if (t + 1 < NT) stage(buf ^ 1, t + 1);

        f16x8 a[4], b[4];
#pragma unroll
        for (int mi = 0; mi < 4; ++mi) {
            const int r = wr * 64 + mi * 16 + lr;
            a[mi] = *(const f16x8*)&As[buf][r * BK + ls * 8];
        }
#pragma unroll
        for (int nj = 0; nj < 4; ++nj) {
            const int c = wc * 64 + nj * 16 + lr;
            b[nj] = *(const f16x8*)&Bs[buf][c * BK + ls * 8];
        }
#pragma unroll
        for (int mi = 0; mi < 4; ++mi)
#pragma unroll
            for (int nj = 0; nj < 4; ++nj)
                acc[mi][nj] = __builtin_amdgcn_mfma_f32_16x16x32_f16(
                    a[mi], b[nj], acc[mi][nj], 0, 0, 0);

        __syncthreads();
    }

    // ---- Epilogue ----
    // C/D layout: col = lane&15 (lr), row = (lane>>4)*4 + reg (ls*4+r).

    // 1) exp2 in place.
#pragma unroll
    for (int mi = 0; mi < 4; ++mi)
#pragma unroll
        for (int nj = 0; nj < 4; ++nj)
#pragma unroll
            for (int r = 0; r < 4; ++r)
                acc[mi][nj][r] = __builtin_amdgcn_exp2f(acc[mi][nj][r] * EXP2_SCALE);

    // 2) row partial sums -> atomic.
#pragma unroll
    for (int mi = 0; mi < 4; ++mi) {
#pragma unroll
        for (int r = 0; r < 4; ++r) {
            float psum = acc[mi][0][r] + acc[mi][1][r] + acc[mi][2][r] + acc[mi][3][r];
            psum += __shfl_xor(psum, 1, 64);
            psum += __shfl_xor(psum, 2, 64);
            psum += __shfl_xor(psum, 4, 64);
            psum += __shfl_xor(psum, 8, 64);
            if (lr == 0)
                atomicAdd(&rowsum[bz * NQ + brow + wr * 64 + mi * 16 + ls * 4 + r], psum);
        }
    }

    // 3) coalesced fp16 stores via XOR-swizzled LDS bounce.
    //    chunk mi covers rows {wr*64 + mi*16 + rr} x 128 cols; LDS 32x128.
    _Float16* pb = ph + (size_t)bz * NQ * NK;
#pragma unroll
    for (int mi = 0; mi < 4; ++mi) {
#pragma unroll
        for (int nj = 0; nj < 4; ++nj) {
#pragma unroll
            for (int r = 0; r < 4; ++r) {
                const int row = wr * 16 + ls * 4 + r;      // 0..31
                const int col = wc * 64 + nj * 16 + lr;    // 0..127
                const int x   = (row >> 2) & 7;
                Ps[row * 128 + (col ^ (x << 4))] = (_Float16)acc[mi][nj][r];
            }
        }
        __syncthreads();
#pragma unroll
        for (int h = 0; h < 2; ++h) {
            const int row  = h * 16 + (tid >> 4);          // 0..31
            const int c    = tid & 15;
            const int x    = (row >> 2) & 7;
            const int phys = row * 128 + ((((c >> 1) ^ x) << 4) | ((c & 1) * 8));
            f16x8 v = *(const f16x8*)&Ps[phys];
            const int grow = brow + h * 64 + mi * 16 + (row & 15);
            const int gcol = bcol + c * 8;
            *(f16x8*)&pb[(size_t)grow * NK + gcol] = v;
        }
        __syncthreads();
    }
}

// ---------------------------------------------------------------------------
// Kernel 3: out[i] = p[i] / rowsum[row]   (fp16 in, fp32 out, 8 elems/thread)
// ---------------------------------------------------------------------------
__global__ __launch_bounds__(256) void softmax_norm(
    const f16x8* __restrict__ ph, const float* __restrict__ rowsum,
    float4* __restrict__ out, int n8)
{
    int stride = gridDim.x * blockDim.x;
    for (int i = blockIdx.x * blockDim.x + threadIdx.x; i < n8; i += stride) {
        const int row = i >> 8;  // 2048/8 = 256 vec8 per row
        const float inv = 1.0f / rowsum[row];
        f16x8 v = ph[i];
        float4 o0, o1;
        o0.x = (float)v[0] * inv; o0.y = (float)v[1] * inv;
        o0.z = (float)v[2] * inv; o0.w = (float)v[3] * inv;
        o1.x = (float)v[4] * inv; o1.y = (float)v[5] * inv;
        o1.z = (float)v[6] * inv; o1.w = (float)v[7] * inv;
        out[i * 2]     = o0;
        out[i * 2 + 1] = o1;
    }
}

// ---------------------------------------------------------------------------
extern "C" void kernel_launch(void* const* d_in, const int* in_sizes, int n_in,
                              void* d_out, int out_size, void* d_ws, size_t ws_size,
                              hipStream_t stream)
{
    const float* q = (const float*)d_in[0];
    const float* k = (const float*)d_in[1];
    float* out = (float*)d_out;

    const size_t elems = (size_t)BATCH * NQ * DIM;   // 16,777,216 per tensor
    const size_t pelems = (size_t)BATCH * NQ * NK;   // 67,108,864
    _Float16* qh = (_Float16*)d_ws;
    _Float16* kh = qh + elems;
    _Float16* ph = kh + elems;                       // +64 MB, 128 MB long
    float* rowsum = (float*)(ph + pelems);           // +192 MB

    hipMemsetAsync(rowsum, 0, BATCH * NQ * sizeof(float), stream);

    const int n4_each = (int)(elems / 4);
    convert_f32_to_f16<<<2048, 256, 0, stream>>>(
        (const float4*)q, (const float4*)k, (f16x4*)qh, (f16x4*)kh, n4_each);

    dim3 grid(NK / BN, NQ / BM, BATCH);
    qk_exp_gemm<<<grid, 256, 0, stream>>>(qh, kh, ph, rowsum);

    const int n8 = (int)(pelems / 8);
    softmax_norm<<<2048, 256, 0, stream>>>(
        (const f16x8*)ph, rowsum, (float4*)out, n8);
}